// Round 1
// baseline (259.660 us; speedup 1.0000x reference)
//
#include <hip/hip_runtime.h>
#include <math.h>

// Problem constants (fixed by setup_inputs)
constexpr int B   = 32;
constexpr int C   = 256;
constexpr int F   = 64;        // C/4
constexpr int HW  = 64 * 64;   // 4096
constexpr int HW4 = HW / 4;    // 1024 float4 per (b,c)
constexpr int P4  = B * HW4;   // 32768 float4 positions per f
constexpr float EPSV = 1e-5f;

constexpr int SBLOCKS = 32;                 // stats blocks per f
constexpr int SITER   = P4 / (SBLOCKS * 256); // 4 float4 per thread
constexpr int TBLOCKS = P4 / 256;           // 128 transform blocks per f

// ---------------- Kernel 1: per-f 14-way reduction (4 sums + 10 products) ----
__global__ __launch_bounds__(256) void stats_kernel(const float* __restrict__ x,
                                                    float* __restrict__ sums) {
    const int f     = blockIdx.x / SBLOCKS;
    const int chunk = blockIdx.x % SBLOCKS;
    const int tid   = threadIdx.x;

    float acc[14];
#pragma unroll
    for (int i = 0; i < 14; ++i) acc[i] = 0.f;

    const float4* xb = reinterpret_cast<const float4*>(x);

#pragma unroll
    for (int it = 0; it < SITER; ++it) {
        const int p   = chunk * (256 * SITER) + it * 256 + tid; // [0, P4)
        const int b   = p >> 10;        // / HW4
        const int hw4 = p & (HW4 - 1);
        float4 v[4];
#pragma unroll
        for (int q = 0; q < 4; ++q)
            v[q] = xb[(size_t)(b * C + q * F + f) * HW4 + hw4];
#pragma unroll
        for (int l = 0; l < 4; ++l) {
            float e0 = ((const float*)&v[0])[l];
            float e1 = ((const float*)&v[1])[l];
            float e2 = ((const float*)&v[2])[l];
            float e3 = ((const float*)&v[3])[l];
            acc[0] += e0; acc[1] += e1; acc[2] += e2; acc[3] += e3;
            acc[4]  += e0 * e0; acc[5]  += e0 * e1; acc[6]  += e0 * e2; acc[7]  += e0 * e3;
            acc[8]  += e1 * e1; acc[9]  += e1 * e2; acc[10] += e1 * e3;
            acc[11] += e2 * e2; acc[12] += e2 * e3;
            acc[13] += e3 * e3;
        }
    }

    // wave (64-lane) shuffle reduction
#pragma unroll
    for (int i = 0; i < 14; ++i) {
#pragma unroll
        for (int off = 32; off >= 1; off >>= 1)
            acc[i] += __shfl_down(acc[i], off, 64);
    }

    __shared__ float red[4][14];
    const int wave = tid >> 6;
    const int lane = tid & 63;
    if (lane == 0) {
#pragma unroll
        for (int i = 0; i < 14; ++i) red[wave][i] = acc[i];
    }
    __syncthreads();
    if (tid < 14) {
        float t = red[0][tid] + red[1][tid] + red[2][tid] + red[3][tid];
        atomicAdd(&sums[f * 14 + tid], t);
    }
}

// ---------------- Kernel 2: per-f mean/cov/Cholesky/inverse -> M (4x4), c (4) -
__global__ __launch_bounds__(64) void solve_kernel(const float* __restrict__ sums,
                                                   const float* __restrict__ weight, // [4,4,F]
                                                   const float* __restrict__ bias,   // [4,F]
                                                   float* __restrict__ Mc) {         // [F][20]
    const int f = threadIdx.x;
    if (f >= F) return;
    const float invN = 1.0f / (float)(B * HW);

    float m[4];
#pragma unroll
    for (int q = 0; q < 4; ++q) m[q] = sums[f * 14 + q] * invN;

    float cov[4][4];
    {
        int k = 4;
        for (int i = 0; i < 4; ++i)
            for (int j = i; j < 4; ++j) {
                float cij = sums[f * 14 + k] * invN - m[i] * m[j];
                cov[i][j] = cij;
                cov[j][i] = cij;
                ++k;
            }
    }
#pragma unroll
    for (int i = 0; i < 4; ++i) cov[i][i] += EPSV;

    // Cholesky (lower)
    float L[4][4] = {};
    for (int i = 0; i < 4; ++i) {
        for (int j = 0; j <= i; ++j) {
            float s = cov[i][j];
            for (int k = 0; k < j; ++k) s -= L[i][k] * L[j][k];
            if (i == j) L[i][j] = sqrtf(s);
            else        L[i][j] = s / L[j][j];
        }
    }
    // invert lower-triangular L
    float Li[4][4] = {};
    for (int j = 0; j < 4; ++j) {
        Li[j][j] = 1.0f / L[j][j];
        for (int i = j + 1; i < 4; ++i) {
            float s = 0.f;
            for (int k = j; k < i; ++k) s += L[i][k] * Li[k][j];
            Li[i][j] = -s / L[i][i];
        }
    }
    // M = W_f * Li,  c = bias_f - M * m
    float M[4][4];
    for (int i = 0; i < 4; ++i)
        for (int j = 0; j < 4; ++j) {
            float s = 0.f;
            for (int k = 0; k < 4; ++k)
                s += weight[(i * 4 + k) * F + f] * Li[k][j];
            M[i][j] = s;
        }
    for (int i = 0; i < 4; ++i) {
        float ci = bias[i * F + f];
        for (int j = 0; j < 4; ++j) ci -= M[i][j] * m[j];
#pragma unroll
        for (int j = 0; j < 4; ++j) Mc[f * 20 + i * 4 + j] = M[i][j];
        Mc[f * 20 + 16 + i] = ci;
    }
}

// ---------------- Kernel 3: out = M*x + c, float4 over hw ---------------------
__global__ __launch_bounds__(256) void transform_kernel(const float* __restrict__ x,
                                                        const float* __restrict__ Mc,
                                                        float* __restrict__ out) {
    const int f     = blockIdx.x / TBLOCKS;
    const int chunk = blockIdx.x % TBLOCKS;

    __shared__ float sM[20];
    if (threadIdx.x < 20) sM[threadIdx.x] = Mc[f * 20 + threadIdx.x];
    __syncthreads();

    const int p   = chunk * 256 + threadIdx.x; // [0, P4)
    const int b   = p >> 10;
    const int hw4 = p & (HW4 - 1);

    const float4* xb = reinterpret_cast<const float4*>(x);
    float4*       ob = reinterpret_cast<float4*>(out);

    float4 v[4];
#pragma unroll
    for (int q = 0; q < 4; ++q)
        v[q] = xb[(size_t)(b * C + q * F + f) * HW4 + hw4];

#pragma unroll
    for (int i = 0; i < 4; ++i) {
        const float m0 = sM[i * 4 + 0], m1 = sM[i * 4 + 1],
                    m2 = sM[i * 4 + 2], m3 = sM[i * 4 + 3];
        const float ci = sM[16 + i];
        float4 o;
        o.x = ci + m0 * v[0].x + m1 * v[1].x + m2 * v[2].x + m3 * v[3].x;
        o.y = ci + m0 * v[0].y + m1 * v[1].y + m2 * v[2].y + m3 * v[3].y;
        o.z = ci + m0 * v[0].z + m1 * v[1].z + m2 * v[2].z + m3 * v[3].z;
        o.w = ci + m0 * v[0].w + m1 * v[1].w + m2 * v[2].w + m3 * v[3].w;
        ob[(size_t)(b * C + i * F + f) * HW4 + hw4] = o;
    }
}

extern "C" void kernel_launch(void* const* d_in, const int* in_sizes, int n_in,
                              void* d_out, int out_size, void* d_ws, size_t ws_size,
                              hipStream_t stream) {
    const float* x      = (const float*)d_in[0];
    const float* weight = (const float*)d_in[1];
    const float* bias   = (const float*)d_in[2];
    float*       out    = (float*)d_out;

    float* sums = (float*)d_ws;          // F*14 floats
    float* Mc   = sums + F * 14;         // F*20 floats

    hipMemsetAsync(sums, 0, F * 14 * sizeof(float), stream);
    stats_kernel<<<F * SBLOCKS, 256, 0, stream>>>(x, sums);
    solve_kernel<<<1, 64, 0, stream>>>(sums, weight, bias, Mc);
    transform_kernel<<<F * TBLOCKS, 256, 0, stream>>>(x, Mc, out);
}